// Round 3
// baseline (38.220 us; speedup 1.0000x reference)
//
#include <hip/hip_runtime.h>

#define NN 4096
#define DD 512
#define CC 1000

typedef __attribute__((ext_vector_type(8))) __bf16 bf16x8;
typedef __attribute__((ext_vector_type(4))) float f32x4;

__device__ __forceinline__ unsigned short f2bf(float f) {
  unsigned int u = __float_as_uint(f);
  u += 0x7fffu + ((u >> 16) & 1u);   // round-to-nearest-even (no NaN in this data)
  return (unsigned short)(u >> 16);
}

// ---------------- kernel 1: normalize rows -> bf16 X, init out --------------
__global__ __launch_bounds__(256) void knorm(const float* __restrict__ embs,
                                             unsigned short* __restrict__ Xb,
                                             float* __restrict__ out) {
  int tid = threadIdx.x;
  if (blockIdx.x == 0 && tid == 0) out[0] = 0.f;  // stream-ordered before kmain
  int lane = tid & 63;
  int row = blockIdx.x * 4 + (tid >> 6);
  const float* rp = embs + (size_t)row * DD;
  float4 v0 = ((const float4*)rp)[lane * 2];
  float4 v1 = ((const float4*)rp)[lane * 2 + 1];
  float ss = v0.x * v0.x + v0.y * v0.y + v0.z * v0.z + v0.w * v0.w +
             v1.x * v1.x + v1.y * v1.y + v1.z * v1.z + v1.w * v1.w;
  for (int off = 32; off; off >>= 1) ss += __shfl_xor(ss, off);
  float scale = 1.0f / fmaxf(sqrtf(ss), 1e-8f);
  float f[8] = {v0.x, v0.y, v0.z, v0.w, v1.x, v1.y, v1.z, v1.w};
  unsigned int h[8];
#pragma unroll
  for (int i = 0; i < 8; ++i) h[i] = f2bf(f[i] * scale);
  uint4 o;
  o.x = h[0] | (h[1] << 16);
  o.y = h[2] | (h[3] << 16);
  o.z = h[4] | (h[5] << 16);
  o.w = h[6] | (h[7] << 16);
  *(uint4*)(Xb + (size_t)row * DD + lane * 8) = o;
}

// ---------------- kernel 2: triangular fused X @ X^T -> gated loss ----------
// Upper-triangle-of-blocks grid (bx >= by); off-diagonal blocks emit both
// ordered terms (mirrored Aij gather). 128x128 tile, BK=64, DOUBLE-BUFFERED
// 2-phase schedule (T3-minimum): issue next tile's global_load_lds BEFORE
// computing the current tile, single barrier-drain per K-step covers the
// L2 load latency with ~400cy of ds_read+MFMA. Both-sides XOR swizzle
// (byte ^= (r&7)<<4) on stage source + ds_read keeps LDS conflict-free.
__global__ __launch_bounds__(256) void kmain(const unsigned short* __restrict__ Xb,
                                             const int* __restrict__ labels,
                                             const float* __restrict__ Aij,
                                             float* __restrict__ out) {
  __shared__ __align__(16) unsigned short As[2][128 * 64];
  __shared__ __align__(16) unsigned short Bs[2][128 * 64];
  int tid = threadIdx.x;
  int lane = tid & 63;
  int w = tid >> 6;
  int wr = w >> 1, wc = w & 1;

  // decode triangular block index: by = row-block, bx in [by, 32)
  int t = blockIdx.x;
  int by = 0;
  while (t >= (32 - by)) { t -= (32 - by); ++by; }
  int bx = by + t;
  int row0 = by * 128;
  int col0 = bx * 128;
  bool offd = (bx != by);

  // per-thread staging constants (idx = chunk index, r = tile row, swizzled src)
  int sidx[4], ssrc[4];
#pragma unroll
  for (int i = 0; i < 4; ++i) {
    int idx = i * 256 + tid;
    int r = idx >> 3;
    int c = idx & 7;
    sidx[i] = idx;
    ssrc[i] = (size_t)r * DD + (((c * 16) ^ ((r & 7) << 4)) >> 1);
  }

#define STAGE(buf, it)                                                          \
  {                                                                             \
    int k0_ = (it) * 64;                                                        \
    _Pragma("unroll") for (int i = 0; i < 4; ++i) {                             \
      const unsigned short* ga = Xb + (size_t)row0 * DD + ssrc[i] + k0_;        \
      const unsigned short* gb = Xb + (size_t)col0 * DD + ssrc[i] + k0_;        \
      __builtin_amdgcn_global_load_lds(                                         \
          (const __attribute__((address_space(1))) void*)ga,                    \
          (__attribute__((address_space(3))) void*)(As[buf] + sidx[i] * 8), 16, \
          0, 0);                                                                \
      __builtin_amdgcn_global_load_lds(                                         \
          (const __attribute__((address_space(1))) void*)gb,                    \
          (__attribute__((address_space(3))) void*)(Bs[buf] + sidx[i] * 8), 16, \
          0, 0);                                                                \
    }                                                                           \
  }

  f32x4 acc[4][4];
#pragma unroll
  for (int m = 0; m < 4; ++m)
#pragma unroll
    for (int n = 0; n < 4; ++n) acc[m][n] = (f32x4){0.f, 0.f, 0.f, 0.f};

  STAGE(0, 0);
  __syncthreads();  // drains vmcnt(0): buf0 ready

  int buf = 0;
  for (int it = 0; it < DD / 64; ++it) {
    if (it < DD / 64 - 1) STAGE(buf ^ 1, it + 1);  // prefetch issue (in flight)
#pragma unroll
    for (int ks = 0; ks < 2; ++ks) {
      bf16x8 a[4], b[4];
      int kb = ks * 64 + (lane >> 4) * 16;
#pragma unroll
      for (int m = 0; m < 4; ++m) {
        int r = wr * 64 + m * 16 + (lane & 15);
        a[m] = *(const bf16x8*)((const char*)As[buf] + r * 128 + (kb ^ ((r & 7) << 4)));
      }
#pragma unroll
      for (int n = 0; n < 4; ++n) {
        int r = wc * 64 + n * 16 + (lane & 15);
        b[n] = *(const bf16x8*)((const char*)Bs[buf] + r * 128 + (kb ^ ((r & 7) << 4)));
      }
#pragma unroll
      for (int m = 0; m < 4; ++m)
#pragma unroll
        for (int n = 0; n < 4; ++n)
          acc[m][n] = __builtin_amdgcn_mfma_f32_16x16x32_bf16(a[m], b[n], acc[m][n], 0, 0, 0);
    }
    __syncthreads();  // full drain: prefetched buf^1 complete, buf free for reuse
    buf ^= 1;
  }
#undef STAGE

  // fused epilogue: gate on d_emb first (rarely true) so gathers stay behind
  // an exec-masked branch. Off-diagonal blocks also emit the mirrored term.
  float lsum = 0.f;
#pragma unroll
  for (int m = 0; m < 4; ++m) {
#pragma unroll
    for (int n = 0; n < 4; ++n) {
#pragma unroll
      for (int j = 0; j < 4; ++j) {
        float s = acc[m][n][j];
        float de = 1.0f - s;
        if (de < 0.7f) {
          int row = row0 + wr * 64 + m * 16 + ((lane >> 4) * 4 + j);
          int col = col0 + wc * 64 + n * 16 + (lane & 15);
          int lr = labels[row], lc = labels[col];
          float dc = Aij[lr * CC + lc];
          if (dc < 0.7f) {
            float d = de - dc;
            lsum += d * d;
          }
          if (offd) {  // mirrored ordered pair (col,row): same de, transposed Aij
            float dc2 = Aij[lc * CC + lr];
            if (dc2 < 0.7f) {
              float d = de - dc2;
              lsum += d * d;
            }
          }
        }
      }
    }
  }
  for (int off = 32; off; off >>= 1) lsum += __shfl_xor(lsum, off);
  __shared__ float red[4];
  if ((tid & 63) == 0) red[w] = lsum;
  __syncthreads();
  if (tid == 0) {
    float v = (red[0] + red[1] + red[2] + red[3]) * (1.0f / ((float)NN * (float)NN));
    if (v != 0.f) atomicAdd(out, v);
  }
}

extern "C" void kernel_launch(void* const* d_in, const int* in_sizes, int n_in,
                              void* d_out, int out_size, void* d_ws, size_t ws_size,
                              hipStream_t stream) {
  const float* embs = (const float*)d_in[0];
  const int* labels = (const int*)d_in[1];
  const float* Aij = (const float*)d_in[2];
  float* out = (float*)d_out;
  unsigned short* Xb = (unsigned short*)d_ws;  // 4096*512 bf16 = 4 MB

  knorm<<<NN / 4, 256, 0, stream>>>(embs, Xb, out);       // fills Xb, zeroes out
  kmain<<<(32 * 33) / 2, 256, 0, stream>>>(Xb, labels, Aij, out);  // triangle
}

// Round 4
// 29.748 us; speedup vs baseline: 1.2848x; 1.2848x over previous
//
#include <hip/hip_runtime.h>

#define NN 4096
#define DD 512
#define CC 1000
#define NB 64   // 64x64 tiles -> 64 row/col blocks, triangle grid 64*65/2

typedef __attribute__((ext_vector_type(8))) __bf16 bf16x8;
typedef __attribute__((ext_vector_type(4))) float f32x4;

__device__ __forceinline__ unsigned short f2bf(float f) {
  unsigned int u = __float_as_uint(f);
  u += 0x7fffu + ((u >> 16) & 1u);   // round-to-nearest-even (no NaN in this data)
  return (unsigned short)(u >> 16);
}

// ---------------- kernel 1: normalize rows -> bf16 X, init out --------------
__global__ __launch_bounds__(256) void knorm(const float* __restrict__ embs,
                                             unsigned short* __restrict__ Xb,
                                             float* __restrict__ out) {
  int tid = threadIdx.x;
  if (blockIdx.x == 0 && tid == 0) out[0] = 0.f;  // stream-ordered before kmain
  int lane = tid & 63;
  int row = blockIdx.x * 4 + (tid >> 6);
  const float* rp = embs + (size_t)row * DD;
  float4 v0 = ((const float4*)rp)[lane * 2];
  float4 v1 = ((const float4*)rp)[lane * 2 + 1];
  float ss = v0.x * v0.x + v0.y * v0.y + v0.z * v0.z + v0.w * v0.w +
             v1.x * v1.x + v1.y * v1.y + v1.z * v1.z + v1.w * v1.w;
  for (int off = 32; off; off >>= 1) ss += __shfl_xor(ss, off);
  float scale = 1.0f / fmaxf(sqrtf(ss), 1e-8f);
  float f[8] = {v0.x, v0.y, v0.z, v0.w, v1.x, v1.y, v1.z, v1.w};
  unsigned int h[8];
#pragma unroll
  for (int i = 0; i < 8; ++i) h[i] = f2bf(f[i] * scale);
  uint4 o;
  o.x = h[0] | (h[1] << 16);
  o.y = h[2] | (h[3] << 16);
  o.z = h[4] | (h[5] << 16);
  o.w = h[6] | (h[7] << 16);
  *(uint4*)(Xb + (size_t)row * DD + lane * 8) = o;
}

// ---------------- kernel 2: triangular fused X @ X^T -> gated loss ----------
// 64x64 tiles, triangle grid (2080 blocks ~ 8/CU) so inter-block TLP hides
// the per-iteration barrier drains (round-2's 128^2/528-block version was
// 75% stall at 2 blocks/CU). Simple 2-barrier schedule (explicit dbuf
// regressed, round 3). Per-element mirror rule: col>row -> emit both ordered
// terms (Aij gather + transposed gather); col==row -> single term; col<row
// skipped (covered by the transposed element). 4 waves (2x2), each 32x32 out
// = 2x2 frags of mfma_f32_16x16x32_bf16. global_load_lds(16B) staging with
// both-sides XOR swizzle (byte ^= (r&7)<<4).
__global__ __launch_bounds__(256) void kmain(const unsigned short* __restrict__ Xb,
                                             const int* __restrict__ labels,
                                             const float* __restrict__ Aij,
                                             float* __restrict__ out) {
  __shared__ __align__(16) unsigned short As[64 * 64];
  __shared__ __align__(16) unsigned short Bs[64 * 64];
  int tid = threadIdx.x;
  int lane = tid & 63;
  int w = tid >> 6;
  int wr = w >> 1, wc = w & 1;

  // decode triangular block index: by = row-block, bx in [by, NB)
  int t = blockIdx.x;
  int by = 0;
  while (t >= (NB - by)) { t -= (NB - by); ++by; }
  int bx = by + t;
  int row0 = by * 64;
  int col0 = bx * 64;

  f32x4 acc[2][2];
#pragma unroll
  for (int m = 0; m < 2; ++m)
#pragma unroll
    for (int n = 0; n < 2; ++n) acc[m][n] = (f32x4){0.f, 0.f, 0.f, 0.f};

  for (int it = 0; it < DD / 64; ++it) {
    int k0 = it * 64;
    if (it) __syncthreads();
#pragma unroll
    for (int i = 0; i < 2; ++i) {
      int idx = i * 256 + tid;      // 16B chunk index within 64x64 tile (8KB)
      int r = idx >> 3;             // tile row (128B per row)
      int c = idx & 7;              // chunk within row
      int srcE = ((c * 16) ^ ((r & 7) << 4)) >> 1;  // inverse-swizzled src elem
      const unsigned short* ga = Xb + (size_t)(row0 + r) * DD + k0 + srcE;
      const unsigned short* gb = Xb + (size_t)(col0 + r) * DD + k0 + srcE;
      __builtin_amdgcn_global_load_lds(
          (const __attribute__((address_space(1))) void*)ga,
          (__attribute__((address_space(3))) void*)(As + idx * 8), 16, 0, 0);
      __builtin_amdgcn_global_load_lds(
          (const __attribute__((address_space(1))) void*)gb,
          (__attribute__((address_space(3))) void*)(Bs + idx * 8), 16, 0, 0);
    }
    __syncthreads();
#pragma unroll
    for (int ks = 0; ks < 2; ++ks) {
      bf16x8 a[2], b[2];
      int kb = ks * 64 + (lane >> 4) * 16;   // byte offset within 128B row
#pragma unroll
      for (int m = 0; m < 2; ++m) {
        int r = wr * 32 + m * 16 + (lane & 15);
        a[m] = *(const bf16x8*)((const char*)As + r * 128 + (kb ^ ((r & 7) << 4)));
      }
#pragma unroll
      for (int n = 0; n < 2; ++n) {
        int r = wc * 32 + n * 16 + (lane & 15);
        b[n] = *(const bf16x8*)((const char*)Bs + r * 128 + (kb ^ ((r & 7) << 4)));
      }
#pragma unroll
      for (int m = 0; m < 2; ++m)
#pragma unroll
        for (int n = 0; n < 2; ++n)
          acc[m][n] = __builtin_amdgcn_mfma_f32_16x16x32_bf16(a[m], b[n], acc[m][n], 0, 0, 0);
    }
  }

  // fused epilogue: gate on d_emb first (rarely true off-diagonal) so gathers
  // stay behind an exec-masked branch; per-element triangle/mirror rule.
  float lsum = 0.f;
#pragma unroll
  for (int m = 0; m < 2; ++m) {
#pragma unroll
    for (int n = 0; n < 2; ++n) {
#pragma unroll
      for (int j = 0; j < 4; ++j) {
        float s = acc[m][n][j];
        float de = 1.0f - s;
        if (de < 0.7f) {
          int row = row0 + wr * 32 + m * 16 + ((lane >> 4) * 4 + j);
          int col = col0 + wc * 32 + n * 16 + (lane & 15);
          if (col >= row) {
            int lr = labels[row], lc = labels[col];
            float dc = Aij[lr * CC + lc];
            if (dc < 0.7f) {
              float d = de - dc;
              lsum += d * d;
            }
            if (col > row) {  // mirrored ordered pair (col,row)
              float dc2 = Aij[lc * CC + lr];
              if (dc2 < 0.7f) {
                float d = de - dc2;
                lsum += d * d;
              }
            }
          }
        }
      }
    }
  }
  for (int off = 32; off; off >>= 1) lsum += __shfl_xor(lsum, off);
  __shared__ float red[4];
  if ((tid & 63) == 0) red[w] = lsum;
  __syncthreads();
  if (tid == 0) {
    float v = (red[0] + red[1] + red[2] + red[3]) * (1.0f / ((float)NN * (float)NN));
    if (v != 0.f) atomicAdd(out, v);
  }
}

extern "C" void kernel_launch(void* const* d_in, const int* in_sizes, int n_in,
                              void* d_out, int out_size, void* d_ws, size_t ws_size,
                              hipStream_t stream) {
  const float* embs = (const float*)d_in[0];
  const int* labels = (const int*)d_in[1];
  const float* Aij = (const float*)d_in[2];
  float* out = (float*)d_out;
  unsigned short* Xb = (unsigned short*)d_ws;  // 4096*512 bf16 = 4 MB

  knorm<<<NN / 4, 256, 0, stream>>>(embs, Xb, out);            // fills Xb, zeroes out
  kmain<<<(NB * (NB + 1)) / 2, 256, 0, stream>>>(Xb, labels, Aij, out);  // triangle
}